// Round 12
// baseline (4718.755 us; speedup 1.0000x reference)
//
#include <hip/hip_runtime.h>

// 2-layer LSTM (H=64, D=1), N=2048, T=512 — MFMA bf16 3-term split precision.
// R12: CROSS-CU LAYER PIPELINE. 256 blocks x 256 thr (4 waves, 1/SIMD).
//  blocks 0..127   = L1 producer for group g (R6 E-waves verbatim):
//      h1(k) -> LDS planes (own recurrence) AND global ring slot k%D
//      (bf16 hi/lo plane mirror, 4.6KB/step, L2-cache resident).
//  blocks 128..255 = L2 consumer for group g (R6 O-waves verbatim):
//      h1 B-frags loaded from ring (prefetched 1 step ahead), h2 recurrence
//      in LDS, dot -> 128-slot out-ring, flush every 64 steps.
// Sync: per-group flags P (producer steps published) / C (consumer steps
// done) via __hip_atomic RELEASE/ACQUIRE at AGENT scope. __syncthreads'
// vmcnt(0) drain completes ring stores before each P-bump; acquire-loads
// invalidate L1 so ring-slot reuse is safe. Lag window [2, D-1], D=8.
// All 256 blocks co-resident (4 waves, <=43KB LDS) -> no scheduling deadlock.

typedef __attribute__((ext_vector_type(8))) short short8;
typedef __attribute__((ext_vector_type(4))) float f32x4;

#define NT 512
#define XPITCH 2060
#define XP 0                  // producer: 16 * 2060 = 32960
#define H1P 32960             // producer: 4 planes (2buf x hi/lo) x 2304 = 9216
#define H2P 0                 // consumer: 4 planes x 2304 = 9216
#define OPR 9216              // consumer: 128 slots x 256B = 32768
#define LDS_BYTES 42176
#define FLAGS_C_OFF 32768     // ws layout: P flags @0, C flags @32768
#define RING_OFF 65536        // ring entries after flags
#define ENTRY 4608            // hi plane 2304 + lo plane 2304

__device__ __forceinline__ float fast_rcp(float x) { return __builtin_amdgcn_rcpf(x); }
__device__ __forceinline__ unsigned short bf_rne(float f) {
  unsigned u = __float_as_uint(f);
  return (unsigned short)((u + 0x7FFFu + ((u >> 16) & 1u)) >> 16);
}
__device__ __forceinline__ void split8(const float* p, short8& hi, short8& lo) {
#pragma unroll
  for (int e = 0; e < 8; ++e) {
    float v = p[e];
    unsigned short h = bf_rne(v);
    float hf = __uint_as_float(((unsigned)h) << 16);
    hi[e] = (short)h;
    lo[e] = (short)bf_rne(v - hf);
  }
}
__device__ __forceinline__ unsigned cvt_pk(float a, float b) {
  unsigned r;
  asm("v_cvt_pk_bf16_f32 %0, %1, %2" : "=v"(r) : "v"(a), "v"(b));
  return r;
}
__device__ __forceinline__ f32x4 mfma16(short8 a, short8 b, f32x4 c) {
  return __builtin_amdgcn_mfma_f32_16x16x32_bf16(a, b, c, 0, 0, 0);
}
__device__ __forceinline__ void cell(float i, float f, float gg, float o,
                                     float& c, float& h) {
  const float ei = __expf(-i), ef = __expf(-f), eg = __expf(-2.f * gg),
              eo = __expf(-o);
  const float P = (1.f - eg) * fast_rcp((1.f + ei) * (1.f + eg));
  c = fmaf(c, fast_rcp(1.f + ef), P);
  const float cc = fminf(15.f, fmaxf(-15.f, c));
  const float ec = __expf(-2.f * cc);
  h = (1.f - ec) * fast_rcp((1.f + eo) * (1.f + ec));
}

__global__ void lstm2_init(char* __restrict__ ws) {
  const int t = threadIdx.x;
  if (t < 128) *(int*)(ws + t * 256) = 0;
  else *(int*)(ws + FLAGS_C_OFF + (t - 128) * 256) = 0;
}

__global__ __launch_bounds__(256, 1) void lstm2_split(
    const float* __restrict__ y, const float* __restrict__ Wih1,
    const float* __restrict__ Whh1, const float* __restrict__ bih1,
    const float* __restrict__ bhh1, const float* __restrict__ Wih2,
    const float* __restrict__ Whh2, const float* __restrict__ bih2,
    const float* __restrict__ bhh2, const float* __restrict__ Wlin,
    const float* __restrict__ blin, char* __restrict__ ws,
    float* __restrict__ out, int D) {
  extern __shared__ char smem[];
  const int tid = threadIdx.x;
  const int w = tid >> 6;          // wave 0..3
  const int lane = tid & 63;
  const int g = lane >> 4;
  const int s = lane & 15;
  const int bid = blockIdx.x;
  const int grp = bid & 127;
  const int s0 = grp * 16;
  int* Pf = (int*)(ws + grp * 256);
  int* Cf = (int*)(ws + FLAGS_C_OFF + grp * 256);
  char* ring = ws + RING_OFF + (size_t)grp * D * ENTRY;
  const int Dm = D - 1;
  const int bo0 = s * 144 + 16 * g, bo1 = bo0 + 64;
  const int hwr = s * 144 + 32 * w + 8 * g;

  if (bid < 128) {
    // ========================= L1 PRODUCER =========================
    for (int i = tid; i < 16 * 512; i += 256) {
      const int ss = i >> 9, t = i & 511;
      *(float*)(smem + XP + ss * XPITCH + t * 4) = y[(size_t)(s0 + ss) * 512 + t];
    }
    for (int i = tid; i < 9216 / 4; i += 256) *(float*)(smem + H1P + i * 4) = 0.f;
    short8 a1h[4][2], a1l[4][2];
#pragma unroll
    for (int p = 0; p < 4; ++p)
#pragma unroll
      for (int c = 0; c < 2; ++c)
        split8(Whh1 + (size_t)(p * 64 + 16 * w + s) * 64 + 32 * c + 8 * g,
               a1h[p][c], a1l[p][c]);
    float bias1c[4][4], wih1c[4][4];
#pragma unroll
    for (int p = 0; p < 4; ++p)
#pragma unroll
      for (int r = 0; r < 4; ++r) {
        const int row = p * 64 + 16 * w + 4 * g + r;
        bias1c[p][r] = bih1[row] + bhh1[row];
        wih1c[p][r] = Wih1[row];
      }
    float c1[4] = {0.f, 0.f, 0.f, 0.f};
    __syncthreads();
    int lastC = 0;

#pragma unroll 1
    for (int k = 0; k < NT; ++k) {
      if (k >= 1 && tid == 0)
        __hip_atomic_store(Pf, k, __ATOMIC_RELEASE, __HIP_MEMORY_SCOPE_AGENT);
      if (k >= D) {  // backpressure: slot k%D previously held step k-D
        const int need = k - D + 1;
        while (lastC < need) {
          lastC = __hip_atomic_load(Cf, __ATOMIC_ACQUIRE, __HIP_MEMORY_SCOPE_AGENT);
          if (lastC < need) __builtin_amdgcn_s_sleep(8);
        }
      }
      const float x = *(const float*)(smem + XP + s * XPITCH + k * 4);
      const int rp0 = H1P + (((k - 1) & 1) * 2 + 0) * 2304;
      const int rp1 = H1P + (((k - 1) & 1) * 2 + 1) * 2304;
      const short8 Bh0 = *(const short8*)(smem + rp0 + bo0);
      const short8 Bl0 = *(const short8*)(smem + rp1 + bo0);
      const short8 Bh1 = *(const short8*)(smem + rp0 + bo1);
      const short8 Bl1 = *(const short8*)(smem + rp1 + bo1);
      f32x4 acc[4], acx[4];
#pragma unroll
      for (int p = 0; p < 4; ++p) {
#pragma unroll
        for (int r = 0; r < 4; ++r) acc[p][r] = fmaf(wih1c[p][r], x, bias1c[p][r]);
        acx[p] = (f32x4){0.f, 0.f, 0.f, 0.f};
      }
      __builtin_amdgcn_s_setprio(1);
#pragma unroll
      for (int p = 0; p < 4; ++p) acc[p] = mfma16(a1h[p][0], Bh0, acc[p]);
#pragma unroll
      for (int p = 0; p < 4; ++p) acx[p] = mfma16(a1h[p][1], Bh1, acx[p]);
#pragma unroll
      for (int p = 0; p < 4; ++p) acc[p] = mfma16(a1h[p][0], Bl0, acc[p]);
#pragma unroll
      for (int p = 0; p < 4; ++p) acx[p] = mfma16(a1h[p][1], Bl1, acx[p]);
#pragma unroll
      for (int p = 0; p < 4; ++p) acc[p] = mfma16(a1l[p][0], Bh0, acc[p]);
#pragma unroll
      for (int p = 0; p < 4; ++p) acx[p] = mfma16(a1l[p][1], Bh1, acx[p]);
      __builtin_amdgcn_s_setprio(0);
#pragma unroll
      for (int p = 0; p < 4; ++p) acc[p] += acx[p];

      float h1n[4];
#pragma unroll
      for (int r = 0; r < 4; ++r)
        cell(acc[0][r], acc[1][r], acc[2][r], acc[3][r], c1[r], h1n[r]);
      const unsigned hA = cvt_pk(h1n[0], h1n[1]), hB = cvt_pk(h1n[2], h1n[3]);
      const unsigned lA = cvt_pk(h1n[0] - __uint_as_float(hA << 16),
                                 h1n[1] - __uint_as_float(hA & 0xFFFF0000u));
      const unsigned lB = cvt_pk(h1n[2] - __uint_as_float(hB << 16),
                                 h1n[3] - __uint_as_float(hB & 0xFFFF0000u));
      const int wp0 = H1P + ((k & 1) * 2 + 0) * 2304;
      const int wp1 = H1P + ((k & 1) * 2 + 1) * 2304;
      *(uint2*)(smem + wp0 + hwr) = make_uint2(hA, hB);
      *(uint2*)(smem + wp1 + hwr) = make_uint2(lA, lB);
      char* rb = ring + (size_t)(k & Dm) * ENTRY;   // global ring mirror
      *(uint2*)(rb + hwr) = make_uint2(hA, hB);
      *(uint2*)(rb + 2304 + hwr) = make_uint2(lA, lB);
      __syncthreads();  // drains vmcnt -> ring stores complete before P-bump
    }
    if (tid == 0)
      __hip_atomic_store(Pf, NT, __ATOMIC_RELEASE, __HIP_MEMORY_SCOPE_AGENT);
  } else {
    // ========================= L2 CONSUMER =========================
    for (int i = tid; i < 9216 / 4; i += 256) *(float*)(smem + H2P + i * 4) = 0.f;
    short8 a2h[4][4], a2l[4][4];  // c 0,1 = Wih2 halves; 2,3 = Whh2 halves
#pragma unroll
    for (int p = 0; p < 4; ++p)
#pragma unroll
      for (int c = 0; c < 4; ++c) {
        const float* src = (c < 2)
            ? (Wih2 + (size_t)(p * 64 + 16 * w + s) * 64 + 32 * c + 8 * g)
            : (Whh2 + (size_t)(p * 64 + 16 * w + s) * 64 + 32 * (c - 2) + 8 * g);
        split8(src, a2h[p][c], a2l[p][c]);
      }
    float bias2c[4][4], wlinc[4];
#pragma unroll
    for (int p = 0; p < 4; ++p)
#pragma unroll
      for (int r = 0; r < 4; ++r)
        bias2c[p][r] = bih2[p * 64 + 16 * w + 4 * g + r] +
                       bhh2[p * 64 + 16 * w + 4 * g + r];
#pragma unroll
    for (int r = 0; r < 4; ++r) wlinc[r] = Wlin[16 * w + 4 * g + r];
    const float bl0 = blin[0];
    float c2[4] = {0.f, 0.f, 0.f, 0.f};
    __syncthreads();
    int lastP = 0;
    while (lastP < 1) {
      lastP = __hip_atomic_load(Pf, __ATOMIC_ACQUIRE, __HIP_MEMORY_SCOPE_AGENT);
      if (lastP < 1) __builtin_amdgcn_s_sleep(8);
    }
    short8 cBh0, cBl0, cBh1, cBl1;
    {
      char* rb = ring;  // slot 0
      cBh0 = *(const short8*)(rb + bo0);
      cBl0 = *(const short8*)(rb + 2304 + bo0);
      cBh1 = *(const short8*)(rb + bo1);
      cBl1 = *(const short8*)(rb + 2304 + bo1);
    }

#pragma unroll 1
    for (int j = 0; j < NT; ++j) {
      if (j >= 1 && tid == 0)
        __hip_atomic_store(Cf, j, __ATOMIC_RELEASE, __HIP_MEMORY_SCOPE_AGENT);
      short8 nBh0, nBl0, nBh1, nBl1;
      const bool hasNext = (j < NT - 1);
      if (hasNext) {  // prefetch h1(j+1) frags
        const int need = j + 2;
        while (lastP < need) {
          lastP = __hip_atomic_load(Pf, __ATOMIC_ACQUIRE, __HIP_MEMORY_SCOPE_AGENT);
          if (lastP < need) __builtin_amdgcn_s_sleep(8);
        }
        char* rb = ring + (size_t)((j + 1) & Dm) * ENTRY;
        nBh0 = *(const short8*)(rb + bo0);
        nBl0 = *(const short8*)(rb + 2304 + bo0);
        nBh1 = *(const short8*)(rb + bo1);
        nBl1 = *(const short8*)(rb + 2304 + bo1);
      }
      if (j >= 65 && (j & 63) == 1) {  // flush out positions [j-65, j-2]
        const int f0 = j - 65;
        const int s2 = tid & 15, gq = tid >> 4;
        float* ob = out + (size_t)(s0 + s2) * 511;
#pragma unroll
        for (int u = 0; u < 4; ++u) {
          const int p = f0 + gq * 4 + u;
          const char* op = smem + OPR + (p & 127) * 256 + s2 * 4;
          ob[p] = *(const float*)(op) + *(const float*)(op + 64) +
                  *(const float*)(op + 128) + *(const float*)(op + 192) + bl0;
        }
      }
      const int rq0 = H2P + (((j - 1) & 1) * 2 + 0) * 2304;  // h2(j-1)
      const int rq1 = H2P + (((j - 1) & 1) * 2 + 1) * 2304;
      const short8 Ch0 = *(const short8*)(smem + rq0 + bo0);
      const short8 Cl0 = *(const short8*)(smem + rq1 + bo0);
      const short8 Ch1 = *(const short8*)(smem + rq0 + bo1);
      const short8 Cl1 = *(const short8*)(smem + rq1 + bo1);
      f32x4 acc[4], acx[4];
#pragma unroll
      for (int p = 0; p < 4; ++p) {
        acc[p] = (f32x4){bias2c[p][0], bias2c[p][1], bias2c[p][2], bias2c[p][3]};
        acx[p] = (f32x4){0.f, 0.f, 0.f, 0.f};
      }
      __builtin_amdgcn_s_setprio(1);
#pragma unroll
      for (int p = 0; p < 4; ++p) acc[p] = mfma16(a2h[p][0], cBh0, acc[p]);
#pragma unroll
      for (int p = 0; p < 4; ++p) acx[p] = mfma16(a2h[p][1], cBh1, acx[p]);
#pragma unroll
      for (int p = 0; p < 4; ++p) acc[p] = mfma16(a2h[p][0], cBl0, acc[p]);
#pragma unroll
      for (int p = 0; p < 4; ++p) acx[p] = mfma16(a2h[p][1], cBl1, acx[p]);
#pragma unroll
      for (int p = 0; p < 4; ++p) acc[p] = mfma16(a2l[p][0], cBh0, acc[p]);
#pragma unroll
      for (int p = 0; p < 4; ++p) acx[p] = mfma16(a2l[p][1], cBh1, acx[p]);
#pragma unroll
      for (int p = 0; p < 4; ++p) acc[p] = mfma16(a2h[p][2], Ch0, acc[p]);
#pragma unroll
      for (int p = 0; p < 4; ++p) acx[p] = mfma16(a2h[p][3], Ch1, acx[p]);
#pragma unroll
      for (int p = 0; p < 4; ++p) acc[p] = mfma16(a2h[p][2], Cl0, acc[p]);
#pragma unroll
      for (int p = 0; p < 4; ++p) acx[p] = mfma16(a2h[p][3], Cl1, acx[p]);
#pragma unroll
      for (int p = 0; p < 4; ++p) acc[p] = mfma16(a2l[p][2], Ch0, acc[p]);
#pragma unroll
      for (int p = 0; p < 4; ++p) acx[p] = mfma16(a2l[p][3], Ch1, acx[p]);
      __builtin_amdgcn_s_setprio(0);
#pragma unroll
      for (int p = 0; p < 4; ++p) acc[p] += acx[p];

      float h2n[4];
#pragma unroll
      for (int r = 0; r < 4; ++r)
        cell(acc[0][r], acc[1][r], acc[2][r], acc[3][r], c2[r], h2n[r]);
      const unsigned hA = cvt_pk(h2n[0], h2n[1]), hB = cvt_pk(h2n[2], h2n[3]);
      const unsigned lA = cvt_pk(h2n[0] - __uint_as_float(hA << 16),
                                 h2n[1] - __uint_as_float(hA & 0xFFFF0000u));
      const unsigned lB = cvt_pk(h2n[2] - __uint_as_float(hB << 16),
                                 h2n[3] - __uint_as_float(hB & 0xFFFF0000u));
      const int wq0 = H2P + ((j & 1) * 2 + 0) * 2304;
      const int wq1 = H2P + ((j & 1) * 2 + 1) * 2304;
      *(uint2*)(smem + wq0 + hwr) = make_uint2(hA, hB);
      *(uint2*)(smem + wq1 + hwr) = make_uint2(lA, lB);
      if (j >= 1) {  // out col j-1 = Wlin . h2(j) + b
        float pw = wlinc[0] * h2n[0];
        pw = fmaf(wlinc[1], h2n[1], pw);
        pw = fmaf(wlinc[2], h2n[2], pw);
        pw = fmaf(wlinc[3], h2n[3], pw);
        pw += __shfl_xor(pw, 16, 64);
        pw += __shfl_xor(pw, 32, 64);
        if (g == 0)
          *(float*)(smem + OPR + ((j - 1) & 127) * 256 + w * 64 + s * 4) = pw;
      }
      __syncthreads();
      if (hasNext) { cBh0 = nBh0; cBl0 = nBl0; cBh1 = nBh1; cBl1 = nBl1; }
    }
    // tail flush: positions 448..510
    {
      const int s2 = tid & 15, gq = tid >> 4;
      float* ob = out + (size_t)(s0 + s2) * 511;
#pragma unroll
      for (int u = 0; u < 4; ++u) {
        const int p = 448 + gq * 4 + u;
        if (p <= 510) {
          const char* op = smem + OPR + (p & 127) * 256 + s2 * 4;
          ob[p] = *(const float*)(op) + *(const float*)(op + 64) +
                  *(const float*)(op + 128) + *(const float*)(op + 192) + bl0;
        }
      }
    }
  }
}

extern "C" void kernel_launch(void* const* d_in, const int* in_sizes, int n_in,
                              void* d_out, int out_size, void* d_ws, size_t ws_size,
                              hipStream_t stream) {
  const float* y    = (const float*)d_in[0];
  const float* Wih1 = (const float*)d_in[1];
  const float* Whh1 = (const float*)d_in[2];
  const float* bih1 = (const float*)d_in[3];
  const float* bhh1 = (const float*)d_in[4];
  const float* Wih2 = (const float*)d_in[5];
  const float* Whh2 = (const float*)d_in[6];
  const float* bih2 = (const float*)d_in[7];
  const float* bhh2 = (const float*)d_in[8];
  const float* Wlin = (const float*)d_in[9];
  const float* blin = (const float*)d_in[10];
  float* out = (float*)d_out;
  char* ws = (char*)d_ws;

  int D = 8;  // ring depth (power of 2, >= 4 for the lag window)
  if (ws_size < (size_t)RING_OFF + (size_t)128 * 8 * ENTRY) D = 4;

  lstm2_init<<<dim3(1), dim3(256), 0, stream>>>(ws);
  hipFuncSetAttribute((const void*)lstm2_split,
                      hipFuncAttributeMaxDynamicSharedMemorySize, LDS_BYTES);
  lstm2_split<<<dim3(256), dim3(256), LDS_BYTES, stream>>>(
      y, Wih1, Whh1, bih1, bhh1, Wih2, Whh2, bih2, bhh2, Wlin, blin, ws, out, D);
}

// Round 13
// 636.349 us; speedup vs baseline: 7.4154x; 7.4154x over previous
//
#include <hip/hip_runtime.h>

// 2-layer LSTM (H=64, D=1), N=2048, T=512 — MFMA bf16 3-term split precision.
// R13 = R6 (champion, 648us) + in-loop VALU cuts, structure untouched:
//  - parity-specialized 2x-unrolled main loop: ALL LDS plane addresses hoisted
//    to loop-invariant registers (indexed by compile-time parity)
//  - exp2 prescale: log2e (2*log2e for gate g) folded into weights/biases at
//    setup; cell uses raw v_exp_f32 (saves the mul inside every __expf)
//  - O's bias vector is the first MFMA's C operand (no acc-init movs)
// 128 blocks x 512 threads (8 waves, 2/SIMD). E waves 0-3 = L1 step k;
// O waves 4-7 = L2 step k-1. One __syncthreads per step. h1/h2 planes
// double-buffered by parity; out staged in 128-slot ring, flushed every 64.

typedef __attribute__((ext_vector_type(8))) short short8;
typedef __attribute__((ext_vector_type(4))) float f32x4;

#define NT 512
#define XPITCH 2060              // 515 words (odd) -> conflict-free x reads
#define XP 0                     // 16 * 2060 = 32960
#define HP 32960                 // 8 planes * 2304 = 18432
#define RING 51392               // 128 slots * 256 B (4 ow x 16 s x f32)
#define LDS_BYTES 84160
#define PLANE(layer, buf, hl) (HP + ((((layer) * 2 + (buf)) * 2) + (hl)) * 2304)
#define L2E 1.44269504f
#define N2L2E (-2.8853900817779268f)   // -2*log2(e)

__device__ __forceinline__ float fast_rcp(float x) { return __builtin_amdgcn_rcpf(x); }
__device__ __forceinline__ float exp2_f(float x) {
  float r; asm("v_exp_f32 %0, %1" : "=v"(r) : "v"(x)); return r;
}
__device__ __forceinline__ unsigned short bf_rne(float f) {
  unsigned u = __float_as_uint(f);
  return (unsigned short)((u + 0x7FFFu + ((u >> 16) & 1u)) >> 16);
}
__device__ __forceinline__ void split8sc(const float* p, float sc, short8& hi, short8& lo) {
#pragma unroll
  for (int e = 0; e < 8; ++e) {
    float v = p[e] * sc;
    unsigned short h = bf_rne(v);
    float hf = __uint_as_float(((unsigned)h) << 16);
    hi[e] = (short)h;
    lo[e] = (short)bf_rne(v - hf);
  }
}
__device__ __forceinline__ unsigned cvt_pk(float a, float b) {
  unsigned r;
  asm("v_cvt_pk_bf16_f32 %0, %1, %2" : "=v"(r) : "v"(a), "v"(b));
  return r;
}
__device__ __forceinline__ f32x4 mfma16(short8 a, short8 b, f32x4 c) {
  return __builtin_amdgcn_mfma_f32_16x16x32_bf16(a, b, c, 0, 0, 0);
}
// gates pre-scaled: i,f,o by log2e; g by 2log2e. 5 exp2 + 3 rcp, no muls
// except the c-arg (c is in real units).
__device__ __forceinline__ void cell2(float i, float f, float g, float o,
                                      float& c, float& h) {
  const float ei = exp2_f(-i), ef = exp2_f(-f), eg = exp2_f(-g), eo = exp2_f(-o);
  const float P = (1.f - eg) * fast_rcp((1.f + ei) * (1.f + eg));
  c = fmaf(c, fast_rcp(1.f + ef), P);
  const float cc = fminf(15.f, fmaxf(-15.f, c));
  const float ec = exp2_f(N2L2E * cc);
  h = (1.f - ec) * fast_rcp((1.f + eo) * (1.f + ec));
}

__global__ __launch_bounds__(512, 2) void lstm2_r13(
    const float* __restrict__ y, const float* __restrict__ Wih1,
    const float* __restrict__ Whh1, const float* __restrict__ bih1,
    const float* __restrict__ bhh1, const float* __restrict__ Wih2,
    const float* __restrict__ Whh2, const float* __restrict__ bih2,
    const float* __restrict__ bhh2, const float* __restrict__ Wlin,
    const float* __restrict__ blin, float* __restrict__ out) {
  extern __shared__ char smem[];
  const int tid = threadIdx.x;
  const int w = tid >> 6;          // wave 0..7
  const int lane = tid & 63;
  const int g = lane >> 4;
  const int s = lane & 15;
  const int s0 = blockIdx.x * 16;

  for (int i = tid; i < 16 * 512; i += 512) {
    const int ss = i >> 9, t = i & 511;
    *(float*)(smem + XP + ss * XPITCH + t * 4) = y[(size_t)(s0 + ss) * 512 + t];
  }
  for (int i = tid; i < 18432 / 4; i += 512) *(float*)(smem + HP + i * 4) = 0.f;
  const float bl0 = blin[0];
  __syncthreads();

  const int bo0 = s * 144 + 16 * g, bo1 = bo0 + 64;
  const float gsc[4] = {L2E, L2E, 2.0f * L2E, L2E};

  if (w < 4) {
    // =================== E: layer 1, step k ===================
    short8 a1h[4][2], a1l[4][2];
#pragma unroll
    for (int p = 0; p < 4; ++p)
#pragma unroll
      for (int c = 0; c < 2; ++c)
        split8sc(Whh1 + (size_t)(p * 64 + 16 * w + s) * 64 + 32 * c + 8 * g,
                 gsc[p], a1h[p][c], a1l[p][c]);
    float bias1c[4][4], wih1c[4][4];
#pragma unroll
    for (int p = 0; p < 4; ++p)
#pragma unroll
      for (int r = 0; r < 4; ++r) {
        const int row = p * 64 + 16 * w + 4 * g + r;
        bias1c[p][r] = (bih1[row] + bhh1[row]) * gsc[p];
        wih1c[p][r] = Wih1[row] * gsc[p];
      }
    float c1[4] = {0.f, 0.f, 0.f, 0.f};
    const int hwr0 = s * 144 + 32 * w + 8 * g;

    // hoisted plane offsets, indexed by compile-time parity P = k&1
    int eR[2][4], eW[2][2];
#pragma unroll
    for (int P = 0; P < 2; ++P) {
      const int rb = P ^ 1;
      eR[P][0] = PLANE(0, rb, 0) + bo0;
      eR[P][1] = PLANE(0, rb, 1) + bo0;
      eR[P][2] = PLANE(0, rb, 0) + bo1;
      eR[P][3] = PLANE(0, rb, 1) + bo1;
      eW[P][0] = PLANE(0, P, 0) + hwr0;
      eW[P][1] = PLANE(0, P, 1) + hwr0;
    }

#define EBODY(KK, P)                                                          \
  {                                                                           \
    const float x = *(const float*)(smem + XP + s * XPITCH + (KK) * 4);       \
    const short8 Bh0 = *(const short8*)(smem + eR[P][0]);                     \
    const short8 Bl0 = *(const short8*)(smem + eR[P][1]);                     \
    const short8 Bh1 = *(const short8*)(smem + eR[P][2]);                     \
    const short8 Bl1 = *(const short8*)(smem + eR[P][3]);                     \
    f32x4 acc[4];                                                             \
    _Pragma("unroll") for (int p = 0; p < 4; ++p) {                           \
      _Pragma("unroll") for (int r = 0; r < 4; ++r)                           \
          acc[p][r] = fmaf(wih1c[p][r], x, bias1c[p][r]);                     \
    }                                                                         \
    __builtin_amdgcn_s_setprio(1);                                            \
    _Pragma("unroll") for (int p = 0; p < 4; ++p)                             \
        acc[p] = mfma16(a1h[p][0], Bh0, acc[p]);                              \
    _Pragma("unroll") for (int p = 0; p < 4; ++p)                             \
        acc[p] = mfma16(a1h[p][1], Bh1, acc[p]);                              \
    _Pragma("unroll") for (int p = 0; p < 4; ++p)                             \
        acc[p] = mfma16(a1h[p][0], Bl0, acc[p]);                              \
    _Pragma("unroll") for (int p = 0; p < 4; ++p)                             \
        acc[p] = mfma16(a1h[p][1], Bl1, acc[p]);                              \
    _Pragma("unroll") for (int p = 0; p < 4; ++p)                             \
        acc[p] = mfma16(a1l[p][0], Bh0, acc[p]);                              \
    _Pragma("unroll") for (int p = 0; p < 4; ++p)                             \
        acc[p] = mfma16(a1l[p][1], Bh1, acc[p]);                              \
    __builtin_amdgcn_s_setprio(0);                                            \
    float h1n[4];                                                             \
    _Pragma("unroll") for (int r = 0; r < 4; ++r)                             \
        cell2(acc[0][r], acc[1][r], acc[2][r], acc[3][r], c1[r], h1n[r]);     \
    const unsigned hA = cvt_pk(h1n[0], h1n[1]), hB = cvt_pk(h1n[2], h1n[3]);  \
    const unsigned lA = cvt_pk(h1n[0] - __uint_as_float(hA << 16),            \
                               h1n[1] - __uint_as_float(hA & 0xFFFF0000u));   \
    const unsigned lB = cvt_pk(h1n[2] - __uint_as_float(hB << 16),            \
                               h1n[3] - __uint_as_float(hB & 0xFFFF0000u));   \
    *(uint2*)(smem + eW[P][0]) = make_uint2(hA, hB);                          \
    *(uint2*)(smem + eW[P][1]) = make_uint2(lA, lB);                          \
  }

    EBODY(0, 0);
    __syncthreads();
#pragma unroll 1
    for (int kb = 1; kb <= 509; kb += 2) {
      EBODY(kb, 1);
      __syncthreads();
      EBODY(kb + 1, 0);
      __syncthreads();
    }
    EBODY(511, 1);
    __syncthreads();
    __syncthreads();  // k = 512 iteration (E idle; O computes h2(511))
  } else {
    // =================== O: layer 2, step k-1 ===================
    const int ow = w - 4;
    short8 a2h[4][4], a2l[4][4];  // c 0,1 = Wih2 halves; 2,3 = Whh2 halves
#pragma unroll
    for (int p = 0; p < 4; ++p)
#pragma unroll
      for (int c = 0; c < 4; ++c) {
        const float* src = (c < 2)
            ? (Wih2 + (size_t)(p * 64 + 16 * ow + s) * 64 + 32 * c + 8 * g)
            : (Whh2 + (size_t)(p * 64 + 16 * ow + s) * 64 + 32 * (c - 2) + 8 * g);
        split8sc(src, gsc[p], a2h[p][c], a2l[p][c]);
      }
    f32x4 bias2v[4];
    float wlinc[4];
#pragma unroll
    for (int p = 0; p < 4; ++p)
#pragma unroll
      for (int r = 0; r < 4; ++r) {
        const int row = p * 64 + 16 * ow + 4 * g + r;
        bias2v[p][r] = (bih2[row] + bhh2[row]) * gsc[p];
      }
#pragma unroll
    for (int r = 0; r < 4; ++r) wlinc[r] = Wlin[16 * ow + 4 * g + r];
    float c2[4] = {0.f, 0.f, 0.f, 0.f};
    const int hwr0 = s * 144 + 32 * ow + 8 * g;
    const int ringb = RING + ow * 64 + s * 4;

    int oR[2][8], oW[2][2];
#pragma unroll
    for (int P = 0; P < 2; ++P) {
      oR[P][0] = PLANE(0, P ^ 1, 0) + bo0;  // h1(k-1) hi
      oR[P][1] = PLANE(0, P ^ 1, 1) + bo0;  // lo
      oR[P][2] = PLANE(0, P ^ 1, 0) + bo1;
      oR[P][3] = PLANE(0, P ^ 1, 1) + bo1;
      oR[P][4] = PLANE(1, P, 0) + bo0;      // h2(k-2) hi
      oR[P][5] = PLANE(1, P, 1) + bo0;
      oR[P][6] = PLANE(1, P, 0) + bo1;
      oR[P][7] = PLANE(1, P, 1) + bo1;
      oW[P][0] = PLANE(1, P ^ 1, 0) + hwr0; // h2(k-1)
      oW[P][1] = PLANE(1, P ^ 1, 1) + hwr0;
    }

#define OFLUSH(KK)                                                            \
  if ((KK) >= 66 && (((KK)-2) & 63) == 0) {                                   \
    const int base = (KK)-66;                                                 \
    const int thr = ow * 64 + lane;                                           \
    const int ss2 = thr & 15, grp = thr >> 4;                                 \
    _Pragma("unroll") for (int q = 0; q < 4; ++q) {                           \
      const int idx = base + grp * 4 + q;                                     \
      const char* op = smem + RING + (idx & 127) * 256 + ss2 * 4;             \
      const float v = *(const float*)(op) + *(const float*)(op + 64) +        \
                      *(const float*)(op + 128) + *(const float*)(op + 192) + \
                      bl0;                                                    \
      out[(size_t)(s0 + ss2) * 511 + idx] = v;                                \
    }                                                                         \
  }

#define OBODY(KK, P)                                                          \
  {                                                                           \
    const short8 Bh0 = *(const short8*)(smem + oR[P][0]);                     \
    const short8 Bl0 = *(const short8*)(smem + oR[P][1]);                     \
    const short8 Bh1 = *(const short8*)(smem + oR[P][2]);                     \
    const short8 Bl1 = *(const short8*)(smem + oR[P][3]);                     \
    const short8 Ch0 = *(const short8*)(smem + oR[P][4]);                     \
    const short8 Cl0 = *(const short8*)(smem + oR[P][5]);                     \
    const short8 Ch1 = *(const short8*)(smem + oR[P][6]);                     \
    const short8 Cl1 = *(const short8*)(smem + oR[P][7]);                     \
    f32x4 acc[4];                                                             \
    __builtin_amdgcn_s_setprio(1);                                            \
    _Pragma("unroll") for (int p = 0; p < 4; ++p)                             \
        acc[p] = mfma16(a2h[p][0], Bh0, bias2v[p]);                           \
    _Pragma("unroll") for (int p = 0; p < 4; ++p)                             \
        acc[p] = mfma16(a2h[p][1], Bh1, acc[p]);                              \
    _Pragma("unroll") for (int p = 0; p < 4; ++p)                             \
        acc[p] = mfma16(a2h[p][0], Bl0, acc[p]);                              \
    _Pragma("unroll") for (int p = 0; p < 4; ++p)                             \
        acc[p] = mfma16(a2h[p][1], Bl1, acc[p]);                              \
    _Pragma("unroll") for (int p = 0; p < 4; ++p)                             \
        acc[p] = mfma16(a2l[p][0], Bh0, acc[p]);                              \
    _Pragma("unroll") for (int p = 0; p < 4; ++p)                             \
        acc[p] = mfma16(a2l[p][1], Bh1, acc[p]);                              \
    _Pragma("unroll") for (int p = 0; p < 4; ++p)                             \
        acc[p] = mfma16(a2h[p][2], Ch0, acc[p]);                              \
    _Pragma("unroll") for (int p = 0; p < 4; ++p)                             \
        acc[p] = mfma16(a2h[p][3], Ch1, acc[p]);                              \
    _Pragma("unroll") for (int p = 0; p < 4; ++p)                             \
        acc[p] = mfma16(a2h[p][2], Cl0, acc[p]);                              \
    _Pragma("unroll") for (int p = 0; p < 4; ++p)                             \
        acc[p] = mfma16(a2h[p][3], Cl1, acc[p]);                              \
    _Pragma("unroll") for (int p = 0; p < 4; ++p)                             \
        acc[p] = mfma16(a2l[p][2], Ch0, acc[p]);                              \
    _Pragma("unroll") for (int p = 0; p < 4; ++p)                             \
        acc[p] = mfma16(a2l[p][3], Ch1, acc[p]);                              \
    __builtin_amdgcn_s_setprio(0);                                            \
    float h2n[4];                                                             \
    _Pragma("unroll") for (int r = 0; r < 4; ++r)                             \
        cell2(acc[0][r], acc[1][r], acc[2][r], acc[3][r], c2[r], h2n[r]);     \
    const unsigned hA = cvt_pk(h2n[0], h2n[1]), hB = cvt_pk(h2n[2], h2n[3]);  \
    const unsigned lA = cvt_pk(h2n[0] - __uint_as_float(hA << 16),            \
                               h2n[1] - __uint_as_float(hA & 0xFFFF0000u));   \
    const unsigned lB = cvt_pk(h2n[2] - __uint_as_float(hB << 16),            \
                               h2n[3] - __uint_as_float(hB & 0xFFFF0000u));   \
    *(uint2*)(smem + oW[P][0]) = make_uint2(hA, hB);                          \
    *(uint2*)(smem + oW[P][1]) = make_uint2(lA, lB);                          \
    if ((KK) >= 2) {                                                          \
      float pw = wlinc[0] * h2n[0];                                           \
      pw = fmaf(wlinc[1], h2n[1], pw);                                        \
      pw = fmaf(wlinc[2], h2n[2], pw);                                        \
      pw = fmaf(wlinc[3], h2n[3], pw);                                        \
      pw += __shfl_xor(pw, 16, 64);                                           \
      pw += __shfl_xor(pw, 32, 64);                                           \
      if (g == 0)                                                             \
        *(float*)(smem + ringb + (((KK)-2) & 127) * 256) = pw;                \
    }                                                                         \
  }

    __syncthreads();  // k = 0 (O idle)
#pragma unroll 1
    for (int kb = 1; kb <= 509; kb += 2) {
      OBODY(kb, 1);
      __syncthreads();
      OFLUSH(kb + 1);
      OBODY(kb + 1, 0);
      __syncthreads();
    }
    OBODY(511, 1);
    __syncthreads();
    OBODY(512, 0);
    __syncthreads();
    // tail flush: out positions 448..510
    {
      const int thr = ow * 64 + lane;
      for (int e = thr; e < 63 * 16; e += 256) {
        const int ss2 = e & 15, off = e >> 4;
        const int idx = 448 + off;
        const char* op = smem + RING + (idx & 127) * 256 + ss2 * 4;
        const float v = *(const float*)(op) + *(const float*)(op + 64) +
                        *(const float*)(op + 128) + *(const float*)(op + 192) + bl0;
        out[(size_t)(s0 + ss2) * 511 + idx] = v;
      }
    }
  }
}

extern "C" void kernel_launch(void* const* d_in, const int* in_sizes, int n_in,
                              void* d_out, int out_size, void* d_ws, size_t ws_size,
                              hipStream_t stream) {
  const float* y    = (const float*)d_in[0];
  const float* Wih1 = (const float*)d_in[1];
  const float* Whh1 = (const float*)d_in[2];
  const float* bih1 = (const float*)d_in[3];
  const float* bhh1 = (const float*)d_in[4];
  const float* Wih2 = (const float*)d_in[5];
  const float* Whh2 = (const float*)d_in[6];
  const float* bih2 = (const float*)d_in[7];
  const float* bhh2 = (const float*)d_in[8];
  const float* Wlin = (const float*)d_in[9];
  const float* blin = (const float*)d_in[10];
  float* out = (float*)d_out;

  hipFuncSetAttribute((const void*)lstm2_r13,
                      hipFuncAttributeMaxDynamicSharedMemorySize, LDS_BYTES);
  lstm2_r13<<<dim3(128), dim3(512), LDS_BYTES, stream>>>(
      y, Wih1, Whh1, bih1, bhh1, Wih2, Whh2, bih2, bhh2, Wlin, blin, out);
}